// Round 7
// baseline (2239.982 us; speedup 1.0000x reference)
//
#include <hip/hip_runtime.h>
#include <math.h>

#define BB 128
#define QQ 200
#define CC 92
#define NP1 201              // n+1 (1-based columns/rows, index 0 = sentinel)
#define CMPAD (QQ * QQ + 64) // pad so lanes 50..63 dummy float4 reads stay in-bounds

// ---------------------------------------------------------------------------
// Kernel 1: lse[b,i] = logsumexp(pred_cat[b,i,:]) over C=92 classes
// ---------------------------------------------------------------------------
__global__ void lse_kernel(const float* __restrict__ pc, float* __restrict__ lse) {
    int idx = blockIdx.x * blockDim.x + threadIdx.x;  // over B*Q
    if (idx >= BB * QQ) return;
    const float* row = pc + (size_t)idx * CC;
    float m = -INFINITY;
    for (int c = 0; c < CC; ++c) m = fmaxf(m, row[c]);
    float s = 0.f;
    for (int c = 0; c < CC; ++c) s += expf(row[c] - m);
    lse[idx] = m + logf(s);
}

// ---------------------------------------------------------------------------
// Kernel 2: cost[b,i,j] = CE + SmoothL1*mask
// ---------------------------------------------------------------------------
__global__ void cost_kernel(const float* __restrict__ pc,
                            const float* __restrict__ pb,
                            const int*   __restrict__ tc,
                            const float* __restrict__ tb,
                            const float* __restrict__ lse,
                            float* __restrict__ cost) {
    long idx = blockIdx.x * (long)blockDim.x + threadIdx.x;
    if (idx >= (long)BB * QQ * QQ) return;
    int j = (int)(idx % QQ);
    int i = (int)((idx / QQ) % QQ);
    int b = (int)(idx / ((long)QQ * QQ));
    int cls = tc[b * QQ + j];
    float ce = lse[b * QQ + i] - pc[((size_t)(b * QQ + i)) * CC + cls];
    const float* pbb = pb + ((size_t)(b * QQ + i)) * 4;
    const float* tbb = tb + ((size_t)(b * QQ + j)) * 4;
    float sl1 = 0.f;
#pragma unroll
    for (int k = 0; k < 4; ++k) {
        float d = pbb[k] - tbb[k];
        float ad = fabsf(d);
        sl1 += (ad < 1.f) ? 0.5f * d * d : (ad - 0.5f);
    }
    float mask = (cls != 0) ? 1.f : 0.f;
    cost[idx] = ce + sl1 * mask;
}

// ---------------------------------------------------------------------------
// order-preserving float -> uint mapping (exact lexicographic argmin)
// ---------------------------------------------------------------------------
__device__ __forceinline__ unsigned sortable(float f) {
    unsigned u = __float_as_uint(f);
    return u ^ ((unsigned)((int)u >> 31) | 0x80000000u);
}
__device__ __forceinline__ float unsortable(unsigned hi) {
    unsigned fb = (hi & 0x80000000u) ? (hi ^ 0x80000000u) : ~hi;
    return __uint_as_float(fb);
}
__device__ __forceinline__ unsigned umin_(unsigned a, unsigned b) { return a < b ? a : b; }

// wave64 min-reduce via DPP (row_shr 1/2/4/8, row_bcast 15/31), result
// broadcast from lane 63 as an SGPR. (validated rounds 5)
__device__ __forceinline__ unsigned wave_umin_bcast(unsigned x) {
    unsigned y;
    y = (unsigned)__builtin_amdgcn_update_dpp((int)x, (int)x, 0x111, 0xf, 0xf, false); x = umin_(x, y);
    y = (unsigned)__builtin_amdgcn_update_dpp((int)x, (int)x, 0x112, 0xf, 0xf, false); x = umin_(x, y);
    y = (unsigned)__builtin_amdgcn_update_dpp((int)x, (int)x, 0x114, 0xf, 0xf, false); x = umin_(x, y);
    y = (unsigned)__builtin_amdgcn_update_dpp((int)x, (int)x, 0x118, 0xf, 0xf, false); x = umin_(x, y);
    y = (unsigned)__builtin_amdgcn_update_dpp((int)x, (int)x, 0x142, 0xf, 0xf, false); x = umin_(x, y);
    y = (unsigned)__builtin_amdgcn_update_dpp((int)x, (int)x, 0x143, 0xf, 0xf, false); x = umin_(x, y);
    return (unsigned)__builtin_amdgcn_readlane((int)x, 63);
}

// ---------------------------------------------------------------------------
// Kernel 3: Hungarian (e-maxx JV, reference trajectory bit-for-bit) — one
// 64-lane wave per batch. R7 = R5's proven memory-op ordering (all LDS reads
// at iteration top, AFTER prior updates in program order; NO reads hoisted
// past atomics — R6's prefetch past ds_add was non-deterministic on HW) plus
// the two safe R6 changes:
//  - lane-major ownership: lane t (t<50) owns columns 4t+1..4t+4 => the row
//    read is ONE ds_read_b128, and smallest-j tie-break is one ballot
//    (lowest lane) + lowest slot k — exact jnp.argmin order (j=4t+k+1).
//  - p[]/way[] in per-lane registers via v_readlane (uniform index).
// u[] in LDS; atomicAdd keeps reference bit-exact repeated += delta.
// ---------------------------------------------------------------------------
__global__ __launch_bounds__(64) void hungarian_kernel(const float* __restrict__ cost,
                                                       float* __restrict__ out) {
    const int b = blockIdx.x;
    const int t = threadIdx.x;
    const float* cb = cost + (size_t)b * QQ * QQ;

    __shared__ __align__(16) float cm[CMPAD];
    __shared__ float u[NP1];

    // stage cost matrix into LDS (float4; single wave => in-order DS ops)
    {
        const float4* src = (const float4*)cb;
        float4* dst = (float4*)cm;
        for (int idx = t; idx < QQ * QQ / 4; idx += 64) dst[idx] = src[idx];
    }
    for (int j = t; j < NP1; j += 64) u[j] = 0.f;

    const float INF = 1e9f;
    const bool lv = (t < 50);           // lane owns 4 valid columns iff t < 50

    float v[4]     = {0.f, 0.f, 0.f, 0.f};
    int   pslot[4] = {0, 0, 0, 0};      // p for owned columns (0 = free)
    float minv[4];
    int   waysl[4];
    int   prow[4];
    int   usedm;

    for (int i = 1; i <= QQ; ++i) {
        minv[0] = minv[1] = minv[2] = minv[3] = INF;
        waysl[0] = waysl[1] = waysl[2] = waysl[3] = 0;
        usedm = 0;
        int j0 = 0;
        int i0 = i;                     // p[0] = i (sentinel)
        for (;;) {
            // ---- mark j0 used (owner lane); sentinel j0==0 via lane 0 below
            if (j0 > 0) {
                int sl = (j0 - 1) & 3, ln = (j0 - 1) >> 2;
                if (ln == t) { usedm |= 1 << sl; prow[sl] = i0; }
            }

            // ---- row + dual reads (AFTER all prior updates — R5 ordering)
            float u0 = u[i0];                                   // LDS broadcast
            float4 cr = *(const float4*)(cm + (i0 - 1) * QQ + 4 * t);

            // ---- scan owned columns (gated on !used: way entries freeze)
            unsigned kv[4];
            {
                float cc[4] = {cr.x, cr.y, cr.z, cr.w};
#pragma unroll
                for (int k = 0; k < 4; ++k) {
                    bool act = lv && !(usedm & (1 << k));
                    float cur = cc[k] - u0 - v[k];
                    if (act && cur < minv[k]) { minv[k] = cur; waysl[k] = j0; }
                    kv[k] = act ? sortable(minv[k]) : 0xFFFFFFFFu;
                }
            }
            unsigned lmin = umin_(umin_(kv[0], kv[1]), umin_(kv[2], kv[3]));
            unsigned gmin = wave_umin_bcast(lmin);
            float delta = unsortable(gmin);

            // ---- argmin, smallest-j tie-break: lowest lane then lowest k
            int lk = (kv[0] == lmin) ? 0 : (kv[1] == lmin) ? 1 : (kv[2] == lmin) ? 2 : 3;
            int localj = 4 * t + lk + 1;
            unsigned long long mm = __ballot(lmin == gmin);
            int tstar = (int)__builtin_ctzll(mm);
            int j1 = __builtin_amdgcn_readlane(localj, tstar);

            // ---- updates (identical single-op sequence to reference)
#pragma unroll
            for (int k = 0; k < 4; ++k) {
                if (usedm & (1 << k)) {
                    v[k] -= delta;
                    atomicAdd(&u[prow[k]], delta);   // ds_add_f32, rows distinct
                } else if (lv) {
                    minv[k] -= delta;
                }
            }
            if (t == 0) atomicAdd(&u[i], delta);     // sentinel column 0 (p[0]=i)

            // ---- p[j1] via registers + readlane (j1 uniform)
            {
                int sl = (j1 - 1) & 3, ln = (j1 - 1) >> 2;
                int ps = (sl == 0) ? pslot[0] : (sl == 1) ? pslot[1]
                        : (sl == 2) ? pslot[2] : pslot[3];
                int pi = __builtin_amdgcn_readlane(ps, ln);
                if (pi == 0) { j0 = j1; break; }
                j0 = j1; i0 = pi;
            }
        }

        // ---- augment: flip matching along alternating path (uniform walk;
        //      way/p served from registers via readlane; path entries frozen)
        {
            int jj = j0;
            while (jj != 0) {
                int jm = jj - 1, lm = jm >> 2, sm = jm & 3;
                int ws = (sm == 0) ? waysl[0] : (sm == 1) ? waysl[1]
                        : (sm == 2) ? waysl[2] : waysl[3];
                int jn = __builtin_amdgcn_readlane(ws, lm);
                int pnew;
                if (jn == 0) {
                    pnew = i;                        // p[0] = i (sentinel)
                } else {
                    int jm2 = jn - 1, ln2 = jm2 >> 2, sn = jm2 & 3;
                    int ps2 = (sn == 0) ? pslot[0] : (sn == 1) ? pslot[1]
                             : (sn == 2) ? pslot[2] : pslot[3];
                    pnew = __builtin_amdgcn_readlane(ps2, ln2);
                }
                if (lm == t) pslot[sm] = pnew;
                jj = jn;
            }
        }
    }

    // pslot[k] = row matched to owned column jc; emit per-row matched cost
    if (lv) {
#pragma unroll
        for (int k = 0; k < 4; ++k) {
            int jc = 4 * t + k + 1;
            int row = pslot[k] - 1;
            out[b * QQ + row] = cm[row * QQ + (jc - 1)];
        }
    }
}

// ---------------------------------------------------------------------------
extern "C" void kernel_launch(void* const* d_in, const int* in_sizes, int n_in,
                              void* d_out, int out_size, void* d_ws, size_t ws_size,
                              hipStream_t stream) {
    const float* pred_cat  = (const float*)d_in[0];
    const float* pred_bbox = (const float*)d_in[1];
    const int*   tar_cat   = (const int*)d_in[2];
    const float* tar_bbox  = (const float*)d_in[3];
    float* out = (float*)d_out;

    float* cost = (float*)d_ws;                     // B*Q*Q floats = 20.48 MB
    float* lse  = cost + (size_t)BB * QQ * QQ;      // B*Q floats

    lse_kernel<<<(BB * QQ + 255) / 256, 256, 0, stream>>>(pred_cat, lse);
    cost_kernel<<<((long)BB * QQ * QQ + 255) / 256, 256, 0, stream>>>(
        pred_cat, pred_bbox, tar_cat, tar_bbox, lse, cost);
    hungarian_kernel<<<BB, 64, 0, stream>>>(cost, out);
}

// Round 8
// 1517.266 us; speedup vs baseline: 1.4763x; 1.4763x over previous
//
#include <hip/hip_runtime.h>
#include <math.h>

#define BB 128
#define QQ 200
#define CC 92
#define CMPAD (QQ * QQ + 64) // pad so c3 = crow[192+t] stays in-bounds for t<64

// ---------------------------------------------------------------------------
// Kernel 1: lse[b,i] = logsumexp(pred_cat[b,i,:]) over C=92 classes
// ---------------------------------------------------------------------------
__global__ void lse_kernel(const float* __restrict__ pc, float* __restrict__ lse) {
    int idx = blockIdx.x * blockDim.x + threadIdx.x;  // over B*Q
    if (idx >= BB * QQ) return;
    const float* row = pc + (size_t)idx * CC;
    float m = -INFINITY;
    for (int c = 0; c < CC; ++c) m = fmaxf(m, row[c]);
    float s = 0.f;
    for (int c = 0; c < CC; ++c) s += expf(row[c] - m);
    lse[idx] = m + logf(s);
}

// ---------------------------------------------------------------------------
// Kernel 2: cost[b,i,j] = CE + SmoothL1*mask
// ---------------------------------------------------------------------------
__global__ void cost_kernel(const float* __restrict__ pc,
                            const float* __restrict__ pb,
                            const int*   __restrict__ tc,
                            const float* __restrict__ tb,
                            const float* __restrict__ lse,
                            float* __restrict__ cost) {
    long idx = blockIdx.x * (long)blockDim.x + threadIdx.x;
    if (idx >= (long)BB * QQ * QQ) return;
    int j = (int)(idx % QQ);
    int i = (int)((idx / QQ) % QQ);
    int b = (int)(idx / ((long)QQ * QQ));
    int cls = tc[b * QQ + j];
    float ce = lse[b * QQ + i] - pc[((size_t)(b * QQ + i)) * CC + cls];
    const float* pbb = pb + ((size_t)(b * QQ + i)) * 4;
    const float* tbb = tb + ((size_t)(b * QQ + j)) * 4;
    float sl1 = 0.f;
#pragma unroll
    for (int k = 0; k < 4; ++k) {
        float d = pbb[k] - tbb[k];
        float ad = fabsf(d);
        sl1 += (ad < 1.f) ? 0.5f * d * d : (ad - 0.5f);
    }
    float mask = (cls != 0) ? 1.f : 0.f;
    cost[idx] = ce + sl1 * mask;
}

// ---------------------------------------------------------------------------
// order-preserving float -> uint mapping (exact lexicographic argmin)
// ---------------------------------------------------------------------------
__device__ __forceinline__ unsigned sortable(float f) {
    unsigned u = __float_as_uint(f);
    return u ^ ((unsigned)((int)u >> 31) | 0x80000000u);
}
__device__ __forceinline__ float unsortable(unsigned hi) {
    unsigned fb = (hi & 0x80000000u) ? (hi ^ 0x80000000u) : ~hi;
    return __uint_as_float(fb);
}
__device__ __forceinline__ unsigned umin_(unsigned a, unsigned b) { return a < b ? a : b; }
__device__ __forceinline__ int rdlane_i(int x, int l) { return __builtin_amdgcn_readlane(x, l); }
__device__ __forceinline__ float rdlane_f(float x, int l) {
    return __uint_as_float((unsigned)__builtin_amdgcn_readlane((int)__float_as_uint(x), l));
}

// wave64 min-reduce via DPP (row_shr 1/2/4/8, row_bcast 15/31), result
// broadcast from lane 63 as an SGPR. (validated rounds 5/7)
__device__ __forceinline__ unsigned wave_umin_bcast(unsigned x) {
    unsigned y;
    y = (unsigned)__builtin_amdgcn_update_dpp((int)x, (int)x, 0x111, 0xf, 0xf, false); x = umin_(x, y);
    y = (unsigned)__builtin_amdgcn_update_dpp((int)x, (int)x, 0x112, 0xf, 0xf, false); x = umin_(x, y);
    y = (unsigned)__builtin_amdgcn_update_dpp((int)x, (int)x, 0x114, 0xf, 0xf, false); x = umin_(x, y);
    y = (unsigned)__builtin_amdgcn_update_dpp((int)x, (int)x, 0x118, 0xf, 0xf, false); x = umin_(x, y);
    y = (unsigned)__builtin_amdgcn_update_dpp((int)x, (int)x, 0x142, 0xf, 0xf, false); x = umin_(x, y);
    y = (unsigned)__builtin_amdgcn_update_dpp((int)x, (int)x, 0x143, 0xf, 0xf, false); x = umin_(x, y);
    return (unsigned)__builtin_amdgcn_readlane((int)x, 63);
}

// ---------------------------------------------------------------------------
// Kernel 3: Hungarian (e-maxx JV, reference trajectory bit-for-bit) — one
// 64-lane wave per batch. R8 = R5's k-major layout (4x ds_read_b32, stride-1,
// conflict-free — R7 proved lane-major b128 is 8-way conflicted) + u[] moved
// from LDS into registers:
//   uslot[k] = u of the row matched to owned column 1+t+64k; usent = u of the
//   current phase's sentinel row (u[i]=0 at phase start — a never-matched row
//   is never on an earlier path). While a column is used, its row's u gets
//   exactly one += delta per iteration -> uslot[k] += delta: identical fp op
//   sequence to the reference's u.at[p].add. u[i0] at iteration top comes
//   from the owner lane of j1 via readlane (~10cyc vs ~120 LDS).
// With u[] gone there are NO LDS atomics: LDS is a read-only matrix after
// staging, so the next row's reads are issued right after pi is known
// (before the VALU updates) with no ordering hazard — deterministic by
// construction (R6's nondeterminism came from reads racing ds_add).
// Lane t owns columns j = 1+t+64k (k=0..3; k=3 valid only for t<8).
// ---------------------------------------------------------------------------
__global__ __launch_bounds__(64) void hungarian_kernel(const float* __restrict__ cost,
                                                       float* __restrict__ out) {
    const int b = blockIdx.x;
    const int t = threadIdx.x;
    const float* cb = cost + (size_t)b * QQ * QQ;

    __shared__ __align__(16) float cm[CMPAD];

    // stage cost matrix into LDS (float4; single wave => in-order DS ops)
    {
        const float4* src = (const float4*)cb;
        float4* dst = (float4*)cm;
        for (int idx = t; idx < QQ * QQ / 4; idx += 64) dst[idx] = src[idx];
    }

    const float INF = 1e9f;
    const int nval = (t < 8) ? 4 : 3;   // slot k valid iff 1+t+64k <= 200

    float v[4]     = {0.f, 0.f, 0.f, 0.f};
    int   pslot[4] = {0, 0, 0, 0};      // p for owned columns (0 = free)
    float uslot[4] = {0.f, 0.f, 0.f, 0.f};  // u of row matched to owned column
    float minv[4];
    int   waysl[4];
    int   usedm;
    float usent;

    for (int i = 1; i <= QQ; ++i) {
        minv[0] = minv[1] = minv[2] = minv[3] = INF;
        waysl[0] = waysl[1] = waysl[2] = waysl[3] = 0;
        usedm = 0;
        usent = 0.f;                    // u[i] == 0 at phase start
        int j0 = 0;
        float u0 = 0.f;                 // u[i0] for current iteration
        // row i0 = i data
        const float* crow = cm + (i - 1) * QQ;
        float c0 = crow[t];
        float c1 = crow[64 + t];
        float c2 = crow[128 + t];
        float c3 = crow[192 + t];       // pad keeps this in-bounds

        for (;;) {
            // ---- mark j0 used (owner lane)
            if (j0 > 0) {
                int s = (j0 - 1) >> 6;
                if (((j0 - 1) & 63) == t) usedm |= 1 << s;
            }

            // ---- scan owned columns (gated on !used: way entries freeze)
            unsigned kv0, kv1, kv2, kv3;
            {
                float cur;
                cur = c0 - u0 - v[0];
                if (!(usedm & 1) && cur < minv[0]) { minv[0] = cur; waysl[0] = j0; }
                kv0 = (usedm & 1) ? 0xFFFFFFFFu : sortable(minv[0]);
                cur = c1 - u0 - v[1];
                if (!(usedm & 2) && cur < minv[1]) { minv[1] = cur; waysl[1] = j0; }
                kv1 = (usedm & 2) ? 0xFFFFFFFFu : sortable(minv[1]);
                cur = c2 - u0 - v[2];
                if (!(usedm & 4) && cur < minv[2]) { minv[2] = cur; waysl[2] = j0; }
                kv2 = (usedm & 4) ? 0xFFFFFFFFu : sortable(minv[2]);
                cur = c3 - u0 - v[3];
                if (!(usedm & 8) && t < 8 && cur < minv[3]) { minv[3] = cur; waysl[3] = j0; }
                kv3 = ((usedm & 8) || t >= 8) ? 0xFFFFFFFFu : sortable(minv[3]);
            }

            unsigned gmin = wave_umin_bcast(umin_(umin_(kv0, kv1), umin_(kv2, kv3)));
            float delta = unsortable(gmin);

            // ---- smallest j with minv==delta: k-major, lowest lane
            unsigned long long m0 = __ballot(kv0 == gmin);
            unsigned long long m1 = __ballot(kv1 == gmin);
            unsigned long long m2 = __ballot(kv2 == gmin);
            unsigned long long m3 = __ballot(kv3 == gmin);
            int j1;
            if (m0)      j1 = 1   + (int)__builtin_ctzll(m0);
            else if (m1) j1 = 65  + (int)__builtin_ctzll(m1);
            else if (m2) j1 = 129 + (int)__builtin_ctzll(m2);
            else         j1 = 193 + (int)__builtin_ctzll(m3);

            // ---- matched row + its dual from j1's owner lane (j1 uniform)
            int kk = (j1 - 1) >> 6, ln = (j1 - 1) & 63;
            int   ps = (kk == 0) ? pslot[0] : (kk == 1) ? pslot[1]
                      : (kk == 2) ? pslot[2] : pslot[3];
            float us = (kk == 0) ? uslot[0] : (kk == 1) ? uslot[1]
                      : (kk == 2) ? uslot[2] : uslot[3];
            int   pi  = rdlane_i(ps, ln);
            float u0n = rdlane_f(us, ln);

            // ---- issue next row's reads NOW (cm is immutable: no hazard);
            //      their ~120cyc latency overlaps the update VALU below
            int nr = (pi > 0 ? pi : 1) - 1;
            const float* nrow = cm + nr * QQ;
            float n0 = nrow[t];
            float n1 = nrow[64 + t];
            float n2 = nrow[128 + t];
            float n3 = nrow[192 + t];

            // ---- updates (identical fp-op sequence to reference)
#pragma unroll
            for (int k = 0; k < 4; ++k) {
                if (usedm & (1 << k)) {
                    v[k] -= delta;
                    uslot[k] += delta;               // == u[p[j]] += delta
                } else if (k < nval) {
                    minv[k] -= delta;
                }
            }
            usent += delta;                          // == u[i] += delta (sentinel)

            if (pi == 0) { j0 = j1; break; }
            j0 = j1; u0 = u0n;
            c0 = n0; c1 = n1; c2 = n2; c3 = n3;
        }

        // ---- augment: flip matching along alternating path (uniform walk;
        //      way/p/u served from registers via readlane; entries frozen)
        {
            int jj = j0;
            while (jj != 0) {
                int jm = jj - 1, km = jm >> 6, lm = jm & 63;
                int ws = (km == 0) ? waysl[0] : (km == 1) ? waysl[1]
                        : (km == 2) ? waysl[2] : waysl[3];
                int jn = rdlane_i(ws, lm);
                int pnew; float unew;
                if (jn == 0) {
                    pnew = i;                        // p[0] = i (sentinel)
                    unew = usent;                    // u[i] accumulated this phase
                } else {
                    int jm2 = jn - 1, kn = jm2 >> 6, ln2 = jm2 & 63;
                    int   ps2 = (kn == 0) ? pslot[0] : (kn == 1) ? pslot[1]
                               : (kn == 2) ? pslot[2] : pslot[3];
                    float us2 = (kn == 0) ? uslot[0] : (kn == 1) ? uslot[1]
                               : (kn == 2) ? uslot[2] : uslot[3];
                    pnew = rdlane_i(ps2, ln2);
                    unew = rdlane_f(us2, ln2);
                }
                if (lm == t) { pslot[km] = pnew; uslot[km] = unew; }
                jj = jn;
            }
        }
    }

    // pslot[k] = row matched to owned column jc; emit per-row matched cost
#pragma unroll
    for (int k = 0; k < 4; ++k) {
        if (k < nval) {
            int jc = 1 + t + 64 * k;
            int row = pslot[k] - 1;
            out[b * QQ + row] = cm[row * QQ + (jc - 1)];
        }
    }
}

// ---------------------------------------------------------------------------
extern "C" void kernel_launch(void* const* d_in, const int* in_sizes, int n_in,
                              void* d_out, int out_size, void* d_ws, size_t ws_size,
                              hipStream_t stream) {
    const float* pred_cat  = (const float*)d_in[0];
    const float* pred_bbox = (const float*)d_in[1];
    const int*   tar_cat   = (const int*)d_in[2];
    const float* tar_bbox  = (const float*)d_in[3];
    float* out = (float*)d_out;

    float* cost = (float*)d_ws;                     // B*Q*Q floats = 20.48 MB
    float* lse  = cost + (size_t)BB * QQ * QQ;      // B*Q floats

    lse_kernel<<<(BB * QQ + 255) / 256, 256, 0, stream>>>(pred_cat, lse);
    cost_kernel<<<((long)BB * QQ * QQ + 255) / 256, 256, 0, stream>>>(
        pred_cat, pred_bbox, tar_cat, tar_bbox, lse, cost);
    hungarian_kernel<<<BB, 64, 0, stream>>>(cost, out);
}

// Round 9
// 1462.845 us; speedup vs baseline: 1.5313x; 1.0372x over previous
//
#include <hip/hip_runtime.h>
#include <math.h>

#define BB 128
#define QQ 200
#define CC 92
#define CMPAD (QQ * QQ + 64) // pad so c3 = crow[192+t] stays in-bounds for t<64

// ---------------------------------------------------------------------------
// Kernel 1: lse[b,i] = logsumexp(pred_cat[b,i,:]) over C=92 classes
// ---------------------------------------------------------------------------
__global__ void lse_kernel(const float* __restrict__ pc, float* __restrict__ lse) {
    int idx = blockIdx.x * blockDim.x + threadIdx.x;  // over B*Q
    if (idx >= BB * QQ) return;
    const float* row = pc + (size_t)idx * CC;
    float m = -INFINITY;
    for (int c = 0; c < CC; ++c) m = fmaxf(m, row[c]);
    float s = 0.f;
    for (int c = 0; c < CC; ++c) s += expf(row[c] - m);
    lse[idx] = m + logf(s);
}

// ---------------------------------------------------------------------------
// Kernel 2: cost[b,i,j] = CE + SmoothL1*mask
// ---------------------------------------------------------------------------
__global__ void cost_kernel(const float* __restrict__ pc,
                            const float* __restrict__ pb,
                            const int*   __restrict__ tc,
                            const float* __restrict__ tb,
                            const float* __restrict__ lse,
                            float* __restrict__ cost) {
    long idx = blockIdx.x * (long)blockDim.x + threadIdx.x;
    if (idx >= (long)BB * QQ * QQ) return;
    int j = (int)(idx % QQ);
    int i = (int)((idx / QQ) % QQ);
    int b = (int)(idx / ((long)QQ * QQ));
    int cls = tc[b * QQ + j];
    float ce = lse[b * QQ + i] - pc[((size_t)(b * QQ + i)) * CC + cls];
    const float* pbb = pb + ((size_t)(b * QQ + i)) * 4;
    const float* tbb = tb + ((size_t)(b * QQ + j)) * 4;
    float sl1 = 0.f;
#pragma unroll
    for (int k = 0; k < 4; ++k) {
        float d = pbb[k] - tbb[k];
        float ad = fabsf(d);
        sl1 += (ad < 1.f) ? 0.5f * d * d : (ad - 0.5f);
    }
    float mask = (cls != 0) ? 1.f : 0.f;
    cost[idx] = ce + sl1 * mask;
}

// ---------------------------------------------------------------------------
__device__ __forceinline__ int rdlane_i(int x, int l) { return __builtin_amdgcn_readlane(x, l); }
__device__ __forceinline__ float rdlane_f(float x, int l) {
    return __uint_as_float((unsigned)__builtin_amdgcn_readlane((int)__float_as_uint(x), l));
}

// wave64 float min-reduce via DPP (row_shr 1/2/4/8, row_bcast 15/31), result
// broadcast from lane 63 as an SGPR. Float domain (v_min_f32): jnp.argmin
// compares floats, so equality-ballot against this min reproduces its
// semantics exactly (incl. -0==+0). No NaNs in this data.
__device__ __forceinline__ float wave_fmin_bcast(float x) {
    float y;
#define DPPSTEP(ctrl) \
    y = __uint_as_float((unsigned)__builtin_amdgcn_update_dpp( \
            (int)__float_as_uint(x), (int)__float_as_uint(x), ctrl, 0xf, 0xf, false)); \
    x = fminf(x, y);
    DPPSTEP(0x111) DPPSTEP(0x112) DPPSTEP(0x114) DPPSTEP(0x118)
    DPPSTEP(0x142) DPPSTEP(0x143)
#undef DPPSTEP
    return rdlane_f(x, 63);
}

// ---------------------------------------------------------------------------
// Kernel 3: Hungarian (e-maxx JV, reference trajectory bit-for-bit) — one
// 64-lane wave per batch. R9 = R8 (k-major conflict-free 4x ds_read_b32,
// u/p/way in registers, no LDS writes after staging => deterministic
// prefetch) with the argmin machinery moved to FLOAT domain:
//   kv[k] = used ? 1e9f : minv[k]   (reference's own jnp.where(used,INF,minv))
//   gmin  = wave fmin (v_min_f32 + DPP), delta = gmin directly
//   j1    = smallest j with kv==gmin (float eq; k-major then lowest lane)
// This drops the sortable/unsortable uint round-trip (~25-30 cyc/iter) and
// matches jnp.argmin float semantics exactly.
// Lane t owns columns j = 1+t+64k (k=0..3; k=3 valid only for t<8).
// ---------------------------------------------------------------------------
__global__ __launch_bounds__(64) void hungarian_kernel(const float* __restrict__ cost,
                                                       float* __restrict__ out) {
    const int b = blockIdx.x;
    const int t = threadIdx.x;
    const float* cb = cost + (size_t)b * QQ * QQ;

    __shared__ __align__(16) float cm[CMPAD];

    // stage cost matrix into LDS (float4; single wave => in-order DS ops)
    {
        const float4* src = (const float4*)cb;
        float4* dst = (float4*)cm;
        for (int idx = t; idx < QQ * QQ / 4; idx += 64) dst[idx] = src[idx];
    }

    const float INF = 1e9f;
    const int nval = (t < 8) ? 4 : 3;   // slot k valid iff 1+t+64k <= 200

    float v[4]     = {0.f, 0.f, 0.f, 0.f};
    int   pslot[4] = {0, 0, 0, 0};      // p for owned columns (0 = free)
    float uslot[4] = {0.f, 0.f, 0.f, 0.f};  // u of row matched to owned column
    float minv[4];
    int   waysl[4];
    int   usedm;
    float usent;

    for (int i = 1; i <= QQ; ++i) {
        minv[0] = minv[1] = minv[2] = minv[3] = INF;
        waysl[0] = waysl[1] = waysl[2] = waysl[3] = 0;
        usedm = 0;
        usent = 0.f;                    // u[i] == 0 at phase start
        int j0 = 0;
        float u0 = 0.f;                 // u[i0] for current iteration
        const float* crow = cm + (i - 1) * QQ;
        float c0 = crow[t];
        float c1 = crow[64 + t];
        float c2 = crow[128 + t];
        float c3 = crow[192 + t];       // pad keeps this in-bounds

        for (;;) {
            // ---- mark j0 used (owner lane)
            if (j0 > 0) {
                int s = (j0 - 1) >> 6;
                if (((j0 - 1) & 63) == t) usedm |= 1 << s;
            }

            // ---- scan owned columns (gated on !used: way entries freeze)
            float kv0, kv1, kv2, kv3;
            {
                float cur;
                cur = c0 - u0 - v[0];
                if (!(usedm & 1) && cur < minv[0]) { minv[0] = cur; waysl[0] = j0; }
                kv0 = (usedm & 1) ? INF : minv[0];
                cur = c1 - u0 - v[1];
                if (!(usedm & 2) && cur < minv[1]) { minv[1] = cur; waysl[1] = j0; }
                kv1 = (usedm & 2) ? INF : minv[1];
                cur = c2 - u0 - v[2];
                if (!(usedm & 4) && cur < minv[2]) { minv[2] = cur; waysl[2] = j0; }
                kv2 = (usedm & 4) ? INF : minv[2];
                cur = c3 - u0 - v[3];
                if (!(usedm & 8) && t < 8 && cur < minv[3]) { minv[3] = cur; waysl[3] = j0; }
                kv3 = ((usedm & 8) || t >= 8) ? INF : minv[3];
            }

            float gmin = wave_fmin_bcast(fminf(fminf(kv0, kv1), fminf(kv2, kv3)));
            float delta = gmin;

            // ---- smallest j with kv==gmin: k-major, lowest lane
            unsigned long long m0 = __ballot(kv0 == gmin);
            unsigned long long m1 = __ballot(kv1 == gmin);
            unsigned long long m2 = __ballot(kv2 == gmin);
            unsigned long long m3 = __ballot(kv3 == gmin);
            int j1;
            if (m0)      j1 = 1   + (int)__builtin_ctzll(m0);
            else if (m1) j1 = 65  + (int)__builtin_ctzll(m1);
            else if (m2) j1 = 129 + (int)__builtin_ctzll(m2);
            else         j1 = 193 + (int)__builtin_ctzll(m3);

            // ---- matched row + its dual from j1's owner lane (j1 uniform)
            int kk = (j1 - 1) >> 6, ln = (j1 - 1) & 63;
            int   ps = (kk == 0) ? pslot[0] : (kk == 1) ? pslot[1]
                      : (kk == 2) ? pslot[2] : pslot[3];
            float us = (kk == 0) ? uslot[0] : (kk == 1) ? uslot[1]
                      : (kk == 2) ? uslot[2] : uslot[3];
            int pi = rdlane_i(ps, ln);

            // ---- issue next row's reads NOW (cm immutable: no hazard);
            //      ~120cyc latency overlaps updates + u0n readlane below
            int nr = (pi > 0 ? pi : 1) - 1;
            const float* nrow = cm + nr * QQ;
            float n0 = nrow[t];
            float n1 = nrow[64 + t];
            float n2 = nrow[128 + t];
            float n3 = nrow[192 + t];

            float u0n = rdlane_f(us, ln);

            // ---- updates (identical fp-op sequence to reference)
#pragma unroll
            for (int k = 0; k < 4; ++k) {
                if (usedm & (1 << k)) {
                    v[k] -= delta;
                    uslot[k] += delta;               // == u[p[j]] += delta
                } else if (k < nval) {
                    minv[k] -= delta;
                }
            }
            usent += delta;                          // == u[i] += delta (sentinel)

            if (pi == 0) { j0 = j1; break; }
            j0 = j1; u0 = u0n;
            c0 = n0; c1 = n1; c2 = n2; c3 = n3;
        }

        // ---- augment: flip matching along alternating path (uniform walk;
        //      way/p/u served from registers via readlane; entries frozen)
        {
            int jj = j0;
            while (jj != 0) {
                int jm = jj - 1, km = jm >> 6, lm = jm & 63;
                int ws = (km == 0) ? waysl[0] : (km == 1) ? waysl[1]
                        : (km == 2) ? waysl[2] : waysl[3];
                int jn = rdlane_i(ws, lm);
                int pnew; float unew;
                if (jn == 0) {
                    pnew = i;                        // p[0] = i (sentinel)
                    unew = usent;                    // u[i] accumulated this phase
                } else {
                    int jm2 = jn - 1, kn = jm2 >> 6, ln2 = jm2 & 63;
                    int   ps2 = (kn == 0) ? pslot[0] : (kn == 1) ? pslot[1]
                               : (kn == 2) ? pslot[2] : pslot[3];
                    float us2 = (kn == 0) ? uslot[0] : (kn == 1) ? uslot[1]
                               : (kn == 2) ? uslot[2] : uslot[3];
                    pnew = rdlane_i(ps2, ln2);
                    unew = rdlane_f(us2, ln2);
                }
                if (lm == t) { pslot[km] = pnew; uslot[km] = unew; }
                jj = jn;
            }
        }
    }

    // pslot[k] = row matched to owned column jc; emit per-row matched cost
#pragma unroll
    for (int k = 0; k < 4; ++k) {
        if (k < nval) {
            int jc = 1 + t + 64 * k;
            int row = pslot[k] - 1;
            out[b * QQ + row] = cm[row * QQ + (jc - 1)];
        }
    }
}

// ---------------------------------------------------------------------------
extern "C" void kernel_launch(void* const* d_in, const int* in_sizes, int n_in,
                              void* d_out, int out_size, void* d_ws, size_t ws_size,
                              hipStream_t stream) {
    const float* pred_cat  = (const float*)d_in[0];
    const float* pred_bbox = (const float*)d_in[1];
    const int*   tar_cat   = (const int*)d_in[2];
    const float* tar_bbox  = (const float*)d_in[3];
    float* out = (float*)d_out;

    float* cost = (float*)d_ws;                     // B*Q*Q floats = 20.48 MB
    float* lse  = cost + (size_t)BB * QQ * QQ;      // B*Q floats

    lse_kernel<<<(BB * QQ + 255) / 256, 256, 0, stream>>>(pred_cat, lse);
    cost_kernel<<<((long)BB * QQ * QQ + 255) / 256, 256, 0, stream>>>(
        pred_cat, pred_bbox, tar_cat, tar_bbox, lse, cost);
    hungarian_kernel<<<BB, 64, 0, stream>>>(cost, out);
}